// Round 8
// baseline (391.656 us; speedup 1.0000x reference)
//
#include <hip/hip_runtime.h>

#define NPIX 9216
#define CIN 72
#define CP 96
#define SPLITS 8
#define JCHUNK (NPIX / SPLITS)   // 1152
#define JTILES (JCHUNK / 64)     // 18
#define FGRID (SPLITS * 2 * 48)  // flash grid = 768 (3 blocks/CU, co-resident)
// p = exp2(s*log2e - 32*log2e)  (fixed softmax shift 32; safe to s<120)
#define L2E   1.44269504088896f
#define EXPB  46.1662413084468f

typedef __attribute__((ext_vector_type(8))) short bf16x8;
typedef __attribute__((ext_vector_type(8))) _Float16 f16x8;
typedef __attribute__((ext_vector_type(4))) float f32x4;

#define MFMA_BF16(A,B,C) __builtin_amdgcn_mfma_f32_16x16x32_bf16(A,B,C,0,0,0)
#define MFMA_F16(A,B,C)  __builtin_amdgcn_mfma_f32_16x16x32_f16(A,B,C,0,0,0)

static __device__ __forceinline__ unsigned short f2bf(float f) {
  unsigned u = __float_as_uint(f);
  u += 0x7fffu + ((u >> 16) & 1u);
  return (unsigned short)(u >> 16);
}
static __device__ __forceinline__ float bf2f(unsigned short h) {
  return __uint_as_float(((unsigned)h) << 16);
}
static __device__ __forceinline__ unsigned short f2h(float f) {
  _Float16 h = (_Float16)f;
  return *(unsigned short*)&h;
}
// pack trunc-bf16 of (lo,hi) into one dword: [lo.hi16 | hi.hi16]
static __device__ __forceinline__ unsigned pack_bf_trunc(float lo, float hi) {
  return (__float_as_uint(lo) >> 16) | (__float_as_uint(hi) & 0xffff0000u);
}
// async global->LDS DMA, 16B per lane; lds dest = uniform base + lane*16.
// global src is PER-LANE (m173): fragment-order LDS = per-lane gather src.
static __device__ __forceinline__ void load_lds16(const void* g, void* l) {
  __builtin_amdgcn_global_load_lds(
      (const __attribute__((address_space(1))) unsigned int*)g,
      (__attribute__((address_space(3))) unsigned int*)l, 16, 0, 0);
}

// ---------------------------------------------------------------------------
// Kernel 1 (v5): QKV projection — fully-decoupled waves, wprep FUSED.
// R7 conclusion: total = flash + 75±3us across ALL rounds/architectures ->
// the residual is per-launch overhead, not qkv compute. This round probes
// dispatch count (4 -> 2). wprep is absorbed here: each wave converts its
// own W fragments inline from raw float W (bit-identical split-bf16 math;
// ~40 exec-masked float4 loads from the L2-hot 62KB W). WH/WL deleted.
// Also resets the flash arrive/wait counter (runs before flash in stream
// order -> visible at kernel boundary; no reliance on workspace init).
// ---------------------------------------------------------------------------
#define XTS 104   // obuf row stride (ushorts), 208 B

__global__ __launch_bounds__(256) void qkv_kernel(
    const float* __restrict__ x,
    const float* __restrict__ Wq, const float* __restrict__ Wk,
    const float* __restrict__ Wv,
    const float* __restrict__ bq, const float* __restrict__ bk,
    const float* __restrict__ bv,
    unsigned short* __restrict__ QH, unsigned short* __restrict__ KH,
    unsigned short* __restrict__ VG, unsigned* done)
{
  __shared__ __align__(16) unsigned short obuf[4][16 * XTS];  // 13,312 B

  const int t    = threadIdx.x;
  const int ww   = t >> 6;
  const int lane = t & 63;
  const int quad = lane >> 4;
  const int l15  = lane & 15;

  if (blockIdx.x == 0 && t == 0)
    __hip_atomic_store(done, 0u, __ATOMIC_RELAXED, __HIP_MEMORY_SCOPE_AGENT);

  const int task  = blockIdx.x * 4 + ww;   // 0..3455
  const int m     = task % 3;              // 0=Q, 1=K, 2=V
  const int strip = task / 3;              // 0..1151
  const int b     = strip / 576;
  const int n0    = (strip % 576) * 16;

  // ---- X B-frags direct from global (n = l15 = px, k = quad*8+j) ----
  bf16x8 xbh[3], xbl[3];
#pragma unroll
  for (int ks = 0; ks < 3; ++ks) {
#pragma unroll
    for (int j = 0; j < 8; ++j) {
      int c = ks * 32 + quad * 8 + j;
      c = (c < 72) ? c : 71;               // clamp: W cols >=72 are zero
      float v = x[((size_t)b * CIN + c) * NPIX + n0 + l15];
      unsigned short hi = f2bf(v);
      ((unsigned short*)&xbh[ks])[j] = hi;
      ((unsigned short*)&xbl[ks])[j] = f2bf(v - bf2f(hi));
    }
  }

  const float* Wm   = (m == 0) ? Wq : (m == 1) ? Wk : Wv;
  const float* bias = (m == 0) ? bq : (m == 1) ? bk : bv;

  // ---- split-bf16 MFMA; W fragments converted inline from float ----
  f32x4 acc[5];
#pragma unroll
  for (int dm = 0; dm < 5; ++dm) {
    acc[dm] = (f32x4){0.f, 0.f, 0.f, 0.f};
    const int d = dm * 16 + l15;
#pragma unroll
    for (int ks = 0; ks < 3; ++ks) {
      const int c0 = ks * 32 + quad * 8;
      bf16x8 ah = (bf16x8)(short)0, al = (bf16x8)(short)0;
      if (d < 72 && c0 < 72) {             // pad region -> zeros (== old WH/WL)
        float4 wa = *(const float4*)(Wm + d * 72 + c0);
        float4 wb = *(const float4*)(Wm + d * 72 + c0 + 4);
        float wv[8] = {wa.x, wa.y, wa.z, wa.w, wb.x, wb.y, wb.z, wb.w};
#pragma unroll
        for (int j = 0; j < 8; ++j) {
          unsigned short hi = f2bf(wv[j]);
          ((unsigned short*)&ah)[j] = hi;
          ((unsigned short*)&al)[j] = f2bf(wv[j] - bf2f(hi));
        }
      }
      acc[dm] = MFMA_BF16(ah, xbh[ks], acc[dm]);
      acc[dm] = MFMA_BF16(ah, xbl[ks], acc[dm]);
      acc[dm] = MFMA_BF16(al, xbh[ks], acc[dm]);
    }
  }

  if (m < 2) {
    // Q/K: bias + fp16, transpose via wave-private obuf (lgkmcnt only),
    // coalesced uint4 stores (cols 9..11 = zero pad)
    unsigned short* ob = obuf[ww];
#pragma unroll
    for (int dm = 0; dm < 5; ++dm)
#pragma unroll
      for (int r = 0; r < 4; ++r) {
        int d = dm * 16 + quad * 4 + r;
        float v = acc[dm][r] + (d < 72 ? bias[d] : 0.f);
        ob[l15 * XTS + d] = f2h(v);
      }
    unsigned short* outp = (m == 0) ? QH : KH;
    const size_t obase = ((size_t)b * NPIX + n0) * CP;
    uint4 z; z.x = z.y = z.z = z.w = 0u;
    for (int f = lane; f < 192; f += 64) {
      int row = f / 12, col = f % 12;
      *(uint4*)(outp + obase + (size_t)row * CP + col * 8) =
          (col < 10) ? *(const uint4*)(ob + row * XTS + col * 8) : z;
    }
  } else {
    // V: bias + bf16, store [c][n] direct; rows 72..79: ones-row + zeros
#pragma unroll
    for (int dm = 0; dm < 5; ++dm)
#pragma unroll
      for (int r = 0; r < 4; ++r) {
        int d = dm * 16 + quad * 4 + r;
        float v = (d < 72) ? acc[dm][r] + bias[d] : (d == 72 ? 1.0f : 0.f);
        VG[((size_t)b * 80 + d) * NPIX + n0 + l15] = f2bf(v);
      }
  }
}

// ---------------------------------------------------------------------------
// Kernel 2 (v7): flash attention + pooling, combine FUSED via arrive/wait.
// Compute core byte-identical to R5/R7 (best measured 73.0us). New tail:
// agent-release fence -> arrive (atomicAdd) -> acquire-spin to 768 -> fence
// -> each block takes a combine slice. All 768 blocks co-resident by
// construction (LDS 22.5KB -> >=6 blocks/CU capacity; VGPR 76; grid 768)
// so the spin cannot deadlock. Counter reset by qkv each launch (stream
// order). G16/m20: atomics device-scope; fences handle cross-XCD L2.
// ---------------------------------------------------------------------------
#define KCH 12    // K chunks per tile: (tj,ks) = 4x3
#define VCH 10    // V chunks per tile: (nt,js) = 5x2

__global__ __launch_bounds__(256, 3) void flash_kernel(
    const float* __restrict__ x,
    const unsigned short* __restrict__ QH, const unsigned short* __restrict__ KH,
    const unsigned short* __restrict__ VG,
    float* __restrict__ NUM, float* __restrict__ LPART,
    float* __restrict__ out, unsigned* done)
{
  __shared__ __align__(16) unsigned short ls_kh[KCH * 512];  // 12,288 B
  __shared__ __align__(16) unsigned short ls_vs[VCH * 512];  // 10,240 B

  const int t    = threadIdx.x;
  const int w    = t >> 6;
  const int lane = t & 63;
  const int quad = lane >> 4;
  const int l15  = lane & 15;

  const int bid  = blockIdx.x;
  const int sp   = bid & 7;          // split == XCD id (round-robin dispatch)
  const int slot = bid >> 3;
  const int b    = slot / 48;
  const int it   = slot % 48;
  const int i0w  = it * 192 + w * 48;

  // Q fragments (B-operand of S^T scores: n=l15=i, k=quad*8+c)
  f16x8 qh[3][3];
#pragma unroll
  for (int mi = 0; mi < 3; ++mi)
#pragma unroll
    for (int ks = 0; ks < 3; ++ks) {
      size_t off = ((size_t)b * NPIX + i0w + mi * 16 + l15) * CP + ks * 32 + quad * 8;
      qh[mi][ks] = *(const f16x8*)(QH + off);
    }

  f32x4 oacc[3][5];   // O^T[c][i]: c = nt*16+quad*4+r, i = mi*16+l15
#pragma unroll
  for (int mi = 0; mi < 3; ++mi)
#pragma unroll
    for (int nt = 0; nt < 5; ++nt) oacc[mi][nt] = (f32x4){0.f, 0.f, 0.f, 0.f};

  const unsigned short* kpg = KH + ((size_t)b * NPIX + sp * JCHUNK) * CP;
  const unsigned short* vpg = VG + (size_t)b * 80 * NPIX + sp * JCHUNK;

  // per-lane gather source offsets (jt-invariant): this wave's chunks c=w+4k.
  int koff[3], voff[3];
#pragma unroll
  for (int k = 0; k < 3; ++k) {
    int c = w + 4 * k;
    koff[k] = ((c / 3) * 16 + l15) * CP + (c % 3) * 32 + quad * 8;
    int cv = (c < VCH) ? c : 0;
    voff[k] = ((cv >> 1) * 16 + l15) * NPIX + (cv & 1) * 32 + quad * 8;
  }

  for (int jt = 0; jt < JTILES; ++jt, kpg += 64 * CP, vpg += 64) {
    // ---- K tile: 12 fragment-order chunks via DMA (3 per wave) ----
#pragma unroll
    for (int k = 0; k < 3; ++k)
      load_lds16(kpg + koff[k], ls_kh + (w + 4 * k) * 512);
    // ---- V tile: 10 fragment-order chunks via DMA (2-3 per wave) ----
#pragma unroll
    for (int k = 0; k < 3; ++k)
      if (w + 4 * k < VCH)   // wave-uniform guard
        load_lds16(vpg + voff[k], ls_vs + (w + 4 * k) * 512);
    __syncthreads();   // drains vmcnt (all DMA) before LDS reads

#pragma unroll
    for (int js = 0; js < 2; ++js) {
      // ---- S^T for tj = js*2 (->pkA), js*2+1 (->pkB) ----
      uint2 pkA[3], pkB[3];
#pragma unroll
      for (int tjh = 0; tjh < 2; ++tjh) {
        const int tj = js * 2 + tjh;
        f16x8 fkh[3];
#pragma unroll
        for (int ks = 0; ks < 3; ++ks)
          fkh[ks] = *(const f16x8*)(ls_kh + (tj * 3 + ks) * 512 + lane * 8);
#pragma unroll
        for (int mi = 0; mi < 3; ++mi) {
          f32x4 s = (f32x4){0.f, 0.f, 0.f, 0.f};
          s = MFMA_F16(fkh[0], qh[mi][0], s);   // A=K (m=j), B=Q (n=i)
          s = MFMA_F16(fkh[1], qh[mi][1], s);
          s = MFMA_F16(fkh[2], qh[mi][2], s);
          float p0 = __builtin_amdgcn_exp2f(__builtin_fmaf(s[0], L2E, -EXPB));
          float p1 = __builtin_amdgcn_exp2f(__builtin_fmaf(s[1], L2E, -EXPB));
          float p2 = __builtin_amdgcn_exp2f(__builtin_fmaf(s[2], L2E, -EXPB));
          float p3 = __builtin_amdgcn_exp2f(__builtin_fmaf(s[3], L2E, -EXPB));
          uint2 pk;
          pk.x = pack_bf_trunc(p0, p1);
          pk.y = pack_bf_trunc(p2, p3);
          if (tjh == 0) pkA[mi] = pk; else pkB[mi] = pk;
        }
      }

      // ---- P redistribution in-register (validated R4/R5, conflicts=0) ----
      bf16x8 pf[3];
#pragma unroll
      for (int mi = 0; mi < 3; ++mi) {
        unsigned x0 = pkA[mi].x, x1 = pkB[mi].x;
        asm("v_permlane32_swap_b32 %0, %1" : "+v"(x0), "+v"(x1));
        asm("v_permlane16_swap_b32 %0, %1" : "+v"(x0), "+v"(x1));
        unsigned y0 = pkA[mi].y, y1 = pkB[mi].y;
        asm("v_permlane32_swap_b32 %0, %1" : "+v"(y0), "+v"(y1));
        asm("v_permlane16_swap_b32 %0, %1" : "+v"(y0), "+v"(y1));
        uint4 fr;
        fr.x = x0; fr.y = y0; fr.z = x1; fr.w = y1;
        pf[mi] = *(const bf16x8*)&fr;
      }

      // ---- PV half: A = V (m=c incl. ones-row 72), B = P (regs) ----
#pragma unroll
      for (int nt = 0; nt < 5; ++nt) {
        bf16x8 vf = *(const bf16x8*)(ls_vs + (nt * 2 + js) * 512 + lane * 8);
#pragma unroll
        for (int mi = 0; mi < 3; ++mi)
          oacc[mi][nt] = MFMA_BF16(vf, pf[mi], oacc[mi][nt]);
      }
    }
    __syncthreads();   // all K/V LDS reads done before next staging
  }

  // ---- epilogue: L from ones-row; fused factor-4 pooling -> NUM fp32 ----
  const size_t sb = (size_t)(sp * 2 + b);
#pragma unroll
  for (int mi = 0; mi < 3; ++mi) {
    const int i = i0w + mi * 16 + l15;
    if (quad == 2)   // c = 72: the ones-row -> L
      LPART[sb * NPIX + i] = oacc[mi][4][0];
#pragma unroll
    for (int nt = 0; nt < 5; ++nt) {
      int c0 = nt * 16 + quad * 4;
      if (c0 < 72) {
        float num = 0.f;
#pragma unroll
        for (int r = 0; r < 4; ++r)
          num = __builtin_fmaf(x[((size_t)b * CIN + c0 + r) * NPIX + i],
                               oacc[mi][nt][r], num);
        NUM[(sb * 18 + (c0 >> 2)) * NPIX + i] = num;   // g = nt*4+quad
      }
    }
  }

  // ---- grid-wide arrive/wait (all FGRID blocks co-resident) ----
  __threadfence();                     // agent release: NUM/LPART published
  __syncthreads();                     // every thread fenced before signal
  if (t == 0) {
    __hip_atomic_fetch_add(done, 1u, __ATOMIC_RELEASE, __HIP_MEMORY_SCOPE_AGENT);
    unsigned v;
    do {
      __builtin_amdgcn_s_sleep(8);
      v = __hip_atomic_load(done, __ATOMIC_ACQUIRE, __HIP_MEMORY_SCOPE_AGENT);
    } while (v < FGRID);
  }
  __syncthreads();
  __threadfence();                     // acquire side: invalidate stale lines

  // ---- combine phase: out = (sum_s NUM_s) / (sum_s L_s) ----
  int cid = bid * 256 + t;
  if (cid < 2 * 18 * (NPIX / 4)) {
    int n = (cid % (NPIX / 4)) * 4;
    int rest = cid / (NPIX / 4);       // = cb*18 + g
    int g = rest % 18, cb = rest / 18;
    float4 A = make_float4(0.f, 0.f, 0.f, 0.f);
    float4 L = make_float4(0.f, 0.f, 0.f, 0.f);
#pragma unroll
    for (int s = 0; s < SPLITS; ++s) {
      size_t sb2 = (size_t)(s * 2 + cb);
      float4 a = *(const float4*)(NUM + (sb2 * 18 + g) * NPIX + n);
      float4 l = *(const float4*)(LPART + sb2 * NPIX + n);
      A.x += a.x; A.y += a.y; A.z += a.z; A.w += a.w;
      L.x += l.x; L.y += l.y; L.z += l.z; L.w += l.w;
    }
    float4 r;
    r.x = A.x / L.x; r.y = A.y / L.y; r.z = A.z / L.z; r.w = A.w / L.w;
    *(float4*)(out + (size_t)cid * 4) = r;
  }
}

// ---------------------------------------------------------------------------
extern "C" void kernel_launch(void* const* d_in, const int* in_sizes, int n_in,
                              void* d_out, int out_size, void* d_ws, size_t ws_size,
                              hipStream_t stream) {
  const float* x  = (const float*)d_in[0];
  const float* Wq = (const float*)d_in[1];
  const float* bq = (const float*)d_in[2];
  const float* Wk = (const float*)d_in[3];
  const float* bk = (const float*)d_in[4];
  const float* Wv = (const float*)d_in[5];
  const float* bv = (const float*)d_in[6];
  float* out = (float*)d_out;

  char* p = (char*)d_ws;
  const size_t szQK = (size_t)2 * NPIX * CP * 2;
  unsigned short* QH = (unsigned short*)p; p += szQK;
  unsigned short* KH = (unsigned short*)p; p += szQK;
  unsigned short* VG = (unsigned short*)p; p += (size_t)2 * 80 * NPIX * 2;
  float* NUM = (float*)p; p += (size_t)SPLITS * 2 * 18 * NPIX * 4;   // 10.6 MB
  float* LPART = (float*)p; p += (size_t)SPLITS * 2 * NPIX * 4;      // 0.6 MB
  unsigned* done = (unsigned*)p; p += 64;                            // barrier ctr

  qkv_kernel<<<864, 256, 0, stream>>>(x, Wq, Wk, Wv, bq, bk, bv, QH, KH, VG, done);
  flash_kernel<<<FGRID, 256, 0, stream>>>(x, QH, KH, VG, NUM, LPART, out, done);
}

// Round 9
// 249.161 us; speedup vs baseline: 1.5719x; 1.5719x over previous
//
#include <hip/hip_runtime.h>

#define NPIX 9216
#define CIN 72
#define CP 96
#define SPLITS 8
#define JCHUNK (NPIX / SPLITS)   // 1152
#define JTILES (JCHUNK / 64)     // 18
#define FGRID (SPLITS * 2 * 48)  // flash grid = 768
#define NCOMB 64                 // last-arriving blocks that run combine
// p = exp2(s*log2e - 32*log2e)  (fixed softmax shift 32; safe to s<120)
#define L2E   1.44269504088896f
#define EXPB  46.1662413084468f

typedef __attribute__((ext_vector_type(8))) short bf16x8;
typedef __attribute__((ext_vector_type(8))) _Float16 f16x8;
typedef __attribute__((ext_vector_type(4))) float f32x4;

#define MFMA_BF16(A,B,C) __builtin_amdgcn_mfma_f32_16x16x32_bf16(A,B,C,0,0,0)
#define MFMA_F16(A,B,C)  __builtin_amdgcn_mfma_f32_16x16x32_f16(A,B,C,0,0,0)

static __device__ __forceinline__ unsigned short f2bf(float f) {
  unsigned u = __float_as_uint(f);
  u += 0x7fffu + ((u >> 16) & 1u);
  return (unsigned short)(u >> 16);
}
static __device__ __forceinline__ float bf2f(unsigned short h) {
  return __uint_as_float(((unsigned)h) << 16);
}
static __device__ __forceinline__ unsigned short f2h(float f) {
  _Float16 h = (_Float16)f;
  return *(unsigned short*)&h;
}
// pack trunc-bf16 of (lo,hi) into one dword: [lo.hi16 | hi.hi16]
static __device__ __forceinline__ unsigned pack_bf_trunc(float lo, float hi) {
  return (__float_as_uint(lo) >> 16) | (__float_as_uint(hi) & 0xffff0000u);
}
// async global->LDS DMA, 16B per lane; lds dest = uniform base + lane*16.
// global src is PER-LANE (m173): fragment-order LDS = per-lane gather src.
static __device__ __forceinline__ void load_lds16(const void* g, void* l) {
  __builtin_amdgcn_global_load_lds(
      (const __attribute__((address_space(1))) unsigned int*)g,
      (__attribute__((address_space(3))) unsigned int*)l, 16, 0, 0);
}

// ---------------------------------------------------------------------------
// Kernel 1 (v5): QKV projection — fully-decoupled waves, wprep fused
// (validated R8: passed, absmax unchanged). Resets the flash ticket counter
// (runs before flash in stream order).
// ---------------------------------------------------------------------------
#define XTS 104   // obuf row stride (ushorts), 208 B

__global__ __launch_bounds__(256) void qkv_kernel(
    const float* __restrict__ x,
    const float* __restrict__ Wq, const float* __restrict__ Wk,
    const float* __restrict__ Wv,
    const float* __restrict__ bq, const float* __restrict__ bk,
    const float* __restrict__ bv,
    unsigned short* __restrict__ QH, unsigned short* __restrict__ KH,
    unsigned short* __restrict__ VG, unsigned* done)
{
  __shared__ __align__(16) unsigned short obuf[4][16 * XTS];  // 13,312 B

  const int t    = threadIdx.x;
  const int ww   = t >> 6;
  const int lane = t & 63;
  const int quad = lane >> 4;
  const int l15  = lane & 15;

  if (blockIdx.x == 0 && t == 0)
    __hip_atomic_store(done, 0u, __ATOMIC_RELAXED, __HIP_MEMORY_SCOPE_AGENT);

  const int task  = blockIdx.x * 4 + ww;   // 0..3455
  const int m     = task % 3;              // 0=Q, 1=K, 2=V
  const int strip = task / 3;              // 0..1151
  const int b     = strip / 576;
  const int n0    = (strip % 576) * 16;

  // ---- X B-frags direct from global (n = l15 = px, k = quad*8+j) ----
  bf16x8 xbh[3], xbl[3];
#pragma unroll
  for (int ks = 0; ks < 3; ++ks) {
#pragma unroll
    for (int j = 0; j < 8; ++j) {
      int c = ks * 32 + quad * 8 + j;
      c = (c < 72) ? c : 71;               // clamp: W cols >=72 are zero
      float v = x[((size_t)b * CIN + c) * NPIX + n0 + l15];
      unsigned short hi = f2bf(v);
      ((unsigned short*)&xbh[ks])[j] = hi;
      ((unsigned short*)&xbl[ks])[j] = f2bf(v - bf2f(hi));
    }
  }

  const float* Wm   = (m == 0) ? Wq : (m == 1) ? Wk : Wv;
  const float* bias = (m == 0) ? bq : (m == 1) ? bk : bv;

  // ---- split-bf16 MFMA; W fragments converted inline from float ----
  f32x4 acc[5];
#pragma unroll
  for (int dm = 0; dm < 5; ++dm) {
    acc[dm] = (f32x4){0.f, 0.f, 0.f, 0.f};
    const int d = dm * 16 + l15;
#pragma unroll
    for (int ks = 0; ks < 3; ++ks) {
      const int c0 = ks * 32 + quad * 8;
      bf16x8 ah = (bf16x8)(short)0, al = (bf16x8)(short)0;
      if (d < 72 && c0 < 72) {             // pad region -> zeros (== old WH/WL)
        float4 wa = *(const float4*)(Wm + d * 72 + c0);
        float4 wb = *(const float4*)(Wm + d * 72 + c0 + 4);
        float wv[8] = {wa.x, wa.y, wa.z, wa.w, wb.x, wb.y, wb.z, wb.w};
#pragma unroll
        for (int j = 0; j < 8; ++j) {
          unsigned short hi = f2bf(wv[j]);
          ((unsigned short*)&ah)[j] = hi;
          ((unsigned short*)&al)[j] = f2bf(wv[j] - bf2f(hi));
        }
      }
      acc[dm] = MFMA_BF16(ah, xbh[ks], acc[dm]);
      acc[dm] = MFMA_BF16(ah, xbl[ks], acc[dm]);
      acc[dm] = MFMA_BF16(al, xbh[ks], acc[dm]);
    }
  }

  if (m < 2) {
    // Q/K: bias + fp16, transpose via wave-private obuf (lgkmcnt only),
    // coalesced uint4 stores (cols 9..11 = zero pad)
    unsigned short* ob = obuf[ww];
#pragma unroll
    for (int dm = 0; dm < 5; ++dm)
#pragma unroll
      for (int r = 0; r < 4; ++r) {
        int d = dm * 16 + quad * 4 + r;
        float v = acc[dm][r] + (d < 72 ? bias[d] : 0.f);
        ob[l15 * XTS + d] = f2h(v);
      }
    unsigned short* outp = (m == 0) ? QH : KH;
    const size_t obase = ((size_t)b * NPIX + n0) * CP;
    uint4 z; z.x = z.y = z.z = z.w = 0u;
    for (int f = lane; f < 192; f += 64) {
      int row = f / 12, col = f % 12;
      *(uint4*)(outp + obase + (size_t)row * CP + col * 8) =
          (col < 10) ? *(const uint4*)(ob + row * XTS + col * 8) : z;
    }
  } else {
    // V: bias + bf16, store [c][n] direct; rows 72..79: ones-row + zeros
#pragma unroll
    for (int dm = 0; dm < 5; ++dm)
#pragma unroll
      for (int r = 0; r < 4; ++r) {
        int d = dm * 16 + quad * 4 + r;
        float v = (d < 72) ? acc[dm][r] + bias[d] : (d == 72 ? 1.0f : 0.f);
        VG[((size_t)b * 80 + d) * NPIX + n0 + l15] = f2bf(v);
      }
  }
}

// ---------------------------------------------------------------------------
// Kernel 2 (v8): flash attention + pooling, combine fused via TICKET barrier.
// R8 post-mortem: the acquire-per-poll spin of 768 blocks caused a device-
// wide cache-invalidation cascade (MfmaUtil 33->7%, flash 74->343us). v8:
//  * each block arrives once (fetch_add, release) -> ticket;
//  * tickets < FGRID-NCOMB EXIT immediately (no spin population, CUs freed;
//    deadlock-free with NO co-residency assumption);
//  * last NCOMB arrivals spin on RELAXED loads (coherent-point read, no
//    invalidation) + s_sleep, one acquire fence, then combine 1/NCOMB slice.
// Flash compute core byte-identical to R5 (best measured 73.0us).
// ---------------------------------------------------------------------------
#define KCH 12    // K chunks per tile: (tj,ks) = 4x3
#define VCH 10    // V chunks per tile: (nt,js) = 5x2

__global__ __launch_bounds__(256, 3) void flash_kernel(
    const float* __restrict__ x,
    const unsigned short* __restrict__ QH, const unsigned short* __restrict__ KH,
    const unsigned short* __restrict__ VG,
    float* __restrict__ NUM, float* __restrict__ LPART,
    float* __restrict__ out, unsigned* done)
{
  __shared__ __align__(16) unsigned short ls_kh[KCH * 512];  // 12,288 B
  __shared__ __align__(16) unsigned short ls_vs[VCH * 512];  // 10,240 B
  __shared__ unsigned tkt;

  const int t    = threadIdx.x;
  const int w    = t >> 6;
  const int lane = t & 63;
  const int quad = lane >> 4;
  const int l15  = lane & 15;

  const int bid  = blockIdx.x;
  const int sp   = bid & 7;          // split == XCD id (round-robin dispatch)
  const int slot = bid >> 3;
  const int b    = slot / 48;
  const int it   = slot % 48;
  const int i0w  = it * 192 + w * 48;

  // Q fragments (B-operand of S^T scores: n=l15=i, k=quad*8+c)
  f16x8 qh[3][3];
#pragma unroll
  for (int mi = 0; mi < 3; ++mi)
#pragma unroll
    for (int ks = 0; ks < 3; ++ks) {
      size_t off = ((size_t)b * NPIX + i0w + mi * 16 + l15) * CP + ks * 32 + quad * 8;
      qh[mi][ks] = *(const f16x8*)(QH + off);
    }

  f32x4 oacc[3][5];   // O^T[c][i]: c = nt*16+quad*4+r, i = mi*16+l15
#pragma unroll
  for (int mi = 0; mi < 3; ++mi)
#pragma unroll
    for (int nt = 0; nt < 5; ++nt) oacc[mi][nt] = (f32x4){0.f, 0.f, 0.f, 0.f};

  const unsigned short* kpg = KH + ((size_t)b * NPIX + sp * JCHUNK) * CP;
  const unsigned short* vpg = VG + (size_t)b * 80 * NPIX + sp * JCHUNK;

  // per-lane gather source offsets (jt-invariant): this wave's chunks c=w+4k.
  int koff[3], voff[3];
#pragma unroll
  for (int k = 0; k < 3; ++k) {
    int c = w + 4 * k;
    koff[k] = ((c / 3) * 16 + l15) * CP + (c % 3) * 32 + quad * 8;
    int cv = (c < VCH) ? c : 0;
    voff[k] = ((cv >> 1) * 16 + l15) * NPIX + (cv & 1) * 32 + quad * 8;
  }

  for (int jt = 0; jt < JTILES; ++jt, kpg += 64 * CP, vpg += 64) {
    // ---- K tile: 12 fragment-order chunks via DMA (3 per wave) ----
#pragma unroll
    for (int k = 0; k < 3; ++k)
      load_lds16(kpg + koff[k], ls_kh + (w + 4 * k) * 512);
    // ---- V tile: 10 fragment-order chunks via DMA (2-3 per wave) ----
#pragma unroll
    for (int k = 0; k < 3; ++k)
      if (w + 4 * k < VCH)   // wave-uniform guard
        load_lds16(vpg + voff[k], ls_vs + (w + 4 * k) * 512);
    __syncthreads();   // drains vmcnt (all DMA) before LDS reads

#pragma unroll
    for (int js = 0; js < 2; ++js) {
      // ---- S^T for tj = js*2 (->pkA), js*2+1 (->pkB) ----
      uint2 pkA[3], pkB[3];
#pragma unroll
      for (int tjh = 0; tjh < 2; ++tjh) {
        const int tj = js * 2 + tjh;
        f16x8 fkh[3];
#pragma unroll
        for (int ks = 0; ks < 3; ++ks)
          fkh[ks] = *(const f16x8*)(ls_kh + (tj * 3 + ks) * 512 + lane * 8);
#pragma unroll
        for (int mi = 0; mi < 3; ++mi) {
          f32x4 s = (f32x4){0.f, 0.f, 0.f, 0.f};
          s = MFMA_F16(fkh[0], qh[mi][0], s);   // A=K (m=j), B=Q (n=i)
          s = MFMA_F16(fkh[1], qh[mi][1], s);
          s = MFMA_F16(fkh[2], qh[mi][2], s);
          float p0 = __builtin_amdgcn_exp2f(__builtin_fmaf(s[0], L2E, -EXPB));
          float p1 = __builtin_amdgcn_exp2f(__builtin_fmaf(s[1], L2E, -EXPB));
          float p2 = __builtin_amdgcn_exp2f(__builtin_fmaf(s[2], L2E, -EXPB));
          float p3 = __builtin_amdgcn_exp2f(__builtin_fmaf(s[3], L2E, -EXPB));
          uint2 pk;
          pk.x = pack_bf_trunc(p0, p1);
          pk.y = pack_bf_trunc(p2, p3);
          if (tjh == 0) pkA[mi] = pk; else pkB[mi] = pk;
        }
      }

      // ---- P redistribution in-register (validated R4/R5, conflicts=0) ----
      bf16x8 pf[3];
#pragma unroll
      for (int mi = 0; mi < 3; ++mi) {
        unsigned x0 = pkA[mi].x, x1 = pkB[mi].x;
        asm("v_permlane32_swap_b32 %0, %1" : "+v"(x0), "+v"(x1));
        asm("v_permlane16_swap_b32 %0, %1" : "+v"(x0), "+v"(x1));
        unsigned y0 = pkA[mi].y, y1 = pkB[mi].y;
        asm("v_permlane32_swap_b32 %0, %1" : "+v"(y0), "+v"(y1));
        asm("v_permlane16_swap_b32 %0, %1" : "+v"(y0), "+v"(y1));
        uint4 fr;
        fr.x = x0; fr.y = y0; fr.z = x1; fr.w = y1;
        pf[mi] = *(const bf16x8*)&fr;
      }

      // ---- PV half: A = V (m=c incl. ones-row 72), B = P (regs) ----
#pragma unroll
      for (int nt = 0; nt < 5; ++nt) {
        bf16x8 vf = *(const bf16x8*)(ls_vs + (nt * 2 + js) * 512 + lane * 8);
#pragma unroll
        for (int mi = 0; mi < 3; ++mi)
          oacc[mi][nt] = MFMA_BF16(vf, pf[mi], oacc[mi][nt]);
      }
    }
    __syncthreads();   // all K/V LDS reads done before next staging
  }

  // ---- epilogue: L from ones-row; fused factor-4 pooling -> NUM fp32 ----
  const size_t sb = (size_t)(sp * 2 + b);
#pragma unroll
  for (int mi = 0; mi < 3; ++mi) {
    const int i = i0w + mi * 16 + l15;
    if (quad == 2)   // c = 72: the ones-row -> L
      LPART[sb * NPIX + i] = oacc[mi][4][0];
#pragma unroll
    for (int nt = 0; nt < 5; ++nt) {
      int c0 = nt * 16 + quad * 4;
      if (c0 < 72) {
        float num = 0.f;
#pragma unroll
        for (int r = 0; r < 4; ++r)
          num = __builtin_fmaf(x[((size_t)b * CIN + c0 + r) * NPIX + i],
                               oacc[mi][nt][r], num);
        NUM[(sb * 18 + (c0 >> 2)) * NPIX + i] = num;   // g = nt*4+quad
      }
    }
  }

  // ---- ticket barrier: early blocks exit; last NCOMB arrivals combine ----
  __threadfence();                     // release: NUM/LPART published
  __syncthreads();                     // every thread fenced before arrive
  if (t == 0)
    tkt = __hip_atomic_fetch_add(done, 1u, __ATOMIC_RELEASE,
                                 __HIP_MEMORY_SCOPE_AGENT);
  __syncthreads();
  const unsigned tk = tkt;
  if (tk < FGRID - NCOMB) return;      // free the CU; no spin population

  if (t == 0) {
    unsigned v;
    do {
      __builtin_amdgcn_s_sleep(16);    // ~0.4us poll; RELAXED = no cache inv
      v = __hip_atomic_load(done, __ATOMIC_RELAXED, __HIP_MEMORY_SCOPE_AGENT);
    } while (v < FGRID);
  }
  __syncthreads();
  __threadfence();                     // acquire: invalidate stale lines once

  // ---- combine phase (last NCOMB blocks): out = sum(NUM)/sum(L) ----
  const int base = (int)(tk - (FGRID - NCOMB));
  for (int cid = base * 256 + t; cid < 2 * 18 * (NPIX / 4); cid += NCOMB * 256) {
    int n = (cid % (NPIX / 4)) * 4;
    int rest = cid / (NPIX / 4);       // = cb*18 + g
    int g = rest % 18, cb = rest / 18;
    float4 A = make_float4(0.f, 0.f, 0.f, 0.f);
    float4 L = make_float4(0.f, 0.f, 0.f, 0.f);
#pragma unroll
    for (int s = 0; s < SPLITS; ++s) {
      size_t sb2 = (size_t)(s * 2 + cb);
      float4 a = *(const float4*)(NUM + (sb2 * 18 + g) * NPIX + n);
      float4 l = *(const float4*)(LPART + sb2 * NPIX + n);
      A.x += a.x; A.y += a.y; A.z += a.z; A.w += a.w;
      L.x += l.x; L.y += l.y; L.z += l.z; L.w += l.w;
    }
    float4 r;
    r.x = A.x / L.x; r.y = A.y / L.y; r.z = A.z / L.z; r.w = A.w / L.w;
    *(float4*)(out + (size_t)cid * 4) = r;
  }
}

// ---------------------------------------------------------------------------
extern "C" void kernel_launch(void* const* d_in, const int* in_sizes, int n_in,
                              void* d_out, int out_size, void* d_ws, size_t ws_size,
                              hipStream_t stream) {
  const float* x  = (const float*)d_in[0];
  const float* Wq = (const float*)d_in[1];
  const float* bq = (const float*)d_in[2];
  const float* Wk = (const float*)d_in[3];
  const float* bk = (const float*)d_in[4];
  const float* Wv = (const float*)d_in[5];
  const float* bv = (const float*)d_in[6];
  float* out = (float*)d_out;

  char* p = (char*)d_ws;
  const size_t szQK = (size_t)2 * NPIX * CP * 2;
  unsigned short* QH = (unsigned short*)p; p += szQK;
  unsigned short* KH = (unsigned short*)p; p += szQK;
  unsigned short* VG = (unsigned short*)p; p += (size_t)2 * 80 * NPIX * 2;
  float* NUM = (float*)p; p += (size_t)SPLITS * 2 * 18 * NPIX * 4;   // 10.6 MB
  float* LPART = (float*)p; p += (size_t)SPLITS * 2 * NPIX * 4;      // 0.6 MB
  unsigned* done = (unsigned*)p; p += 64;                            // barrier ctr

  qkv_kernel<<<864, 256, 0, stream>>>(x, Wq, Wk, Wv, bq, bk, bv, QH, KH, VG, done);
  flash_kernel<<<FGRID, 256, 0, stream>>>(x, QH, KH, VG, NUM, LPART, out, done);
}

// Round 10
// 247.707 us; speedup vs baseline: 1.5811x; 1.0059x over previous
//
#include <hip/hip_runtime.h>

#define NPIX 9216
#define CIN 72
#define CP 96
#define SPLITS 8
#define JCHUNK (NPIX / SPLITS)   // 1152
#define JTILES (JCHUNK / 64)     // 18
#define FGRID (SPLITS * 2 * 48)  // flash grid = 768
#define NCOMB 64                 // last-arriving blocks that run combine
// p = exp2(s*log2e - 32*log2e)  (fixed softmax shift 32; safe to s<120)
#define L2E   1.44269504088896f
#define EXPB  46.1662413084468f

typedef __attribute__((ext_vector_type(8))) short bf16x8;
typedef __attribute__((ext_vector_type(8))) _Float16 f16x8;
typedef __attribute__((ext_vector_type(4))) float f32x4;

#define MFMA_BF16(A,B,C) __builtin_amdgcn_mfma_f32_16x16x32_bf16(A,B,C,0,0,0)
#define MFMA_F16(A,B,C)  __builtin_amdgcn_mfma_f32_16x16x32_f16(A,B,C,0,0,0)

static __device__ __forceinline__ unsigned short f2bf(float f) {
  unsigned u = __float_as_uint(f);
  u += 0x7fffu + ((u >> 16) & 1u);
  return (unsigned short)(u >> 16);
}
static __device__ __forceinline__ float bf2f(unsigned short h) {
  return __uint_as_float(((unsigned)h) << 16);
}
static __device__ __forceinline__ unsigned short f2h(float f) {
  _Float16 h = (_Float16)f;
  return *(unsigned short*)&h;
}
// pack trunc-bf16 of (lo,hi) into one dword: [lo.hi16 | hi.hi16]
static __device__ __forceinline__ unsigned pack_bf_trunc(float lo, float hi) {
  return (__float_as_uint(lo) >> 16) | (__float_as_uint(hi) & 0xffff0000u);
}
// async global->LDS DMA, 16B per lane; lds dest = uniform base + lane*16.
// global src is PER-LANE (m173): fragment-order LDS = per-lane gather src.
static __device__ __forceinline__ void load_lds16(const void* g, void* l) {
  __builtin_amdgcn_global_load_lds(
      (const __attribute__((address_space(1))) unsigned int*)g,
      (__attribute__((address_space(3))) unsigned int*)l, 16, 0, 0);
}

// ---------------------------------------------------------------------------
// Kernel 1 (v5): QKV projection — fully-decoupled waves, wprep fused
// (validated R8/R9). Resets the flash ticket counter (stream order).
// ---------------------------------------------------------------------------
#define XTS 104   // obuf row stride (ushorts), 208 B

__global__ __launch_bounds__(256) void qkv_kernel(
    const float* __restrict__ x,
    const float* __restrict__ Wq, const float* __restrict__ Wk,
    const float* __restrict__ Wv,
    const float* __restrict__ bq, const float* __restrict__ bk,
    const float* __restrict__ bv,
    unsigned short* __restrict__ QH, unsigned short* __restrict__ KH,
    unsigned short* __restrict__ VG, unsigned* done)
{
  __shared__ __align__(16) unsigned short obuf[4][16 * XTS];  // 13,312 B

  const int t    = threadIdx.x;
  const int ww   = t >> 6;
  const int lane = t & 63;
  const int quad = lane >> 4;
  const int l15  = lane & 15;

  if (blockIdx.x == 0 && t == 0)
    __hip_atomic_store(done, 0u, __ATOMIC_RELAXED, __HIP_MEMORY_SCOPE_AGENT);

  const int task  = blockIdx.x * 4 + ww;   // 0..3455
  const int m     = task % 3;              // 0=Q, 1=K, 2=V
  const int strip = task / 3;              // 0..1151
  const int b     = strip / 576;
  const int n0    = (strip % 576) * 16;

  // ---- X B-frags direct from global (n = l15 = px, k = quad*8+j) ----
  bf16x8 xbh[3], xbl[3];
#pragma unroll
  for (int ks = 0; ks < 3; ++ks) {
#pragma unroll
    for (int j = 0; j < 8; ++j) {
      int c = ks * 32 + quad * 8 + j;
      c = (c < 72) ? c : 71;               // clamp: W cols >=72 are zero
      float v = x[((size_t)b * CIN + c) * NPIX + n0 + l15];
      unsigned short hi = f2bf(v);
      ((unsigned short*)&xbh[ks])[j] = hi;
      ((unsigned short*)&xbl[ks])[j] = f2bf(v - bf2f(hi));
    }
  }

  const float* Wm   = (m == 0) ? Wq : (m == 1) ? Wk : Wv;
  const float* bias = (m == 0) ? bq : (m == 1) ? bk : bv;

  // ---- split-bf16 MFMA; W fragments converted inline from float ----
  f32x4 acc[5];
#pragma unroll
  for (int dm = 0; dm < 5; ++dm) {
    acc[dm] = (f32x4){0.f, 0.f, 0.f, 0.f};
    const int d = dm * 16 + l15;
#pragma unroll
    for (int ks = 0; ks < 3; ++ks) {
      const int c0 = ks * 32 + quad * 8;
      bf16x8 ah = (bf16x8)(short)0, al = (bf16x8)(short)0;
      if (d < 72 && c0 < 72) {             // pad region -> zeros (== old WH/WL)
        float4 wa = *(const float4*)(Wm + d * 72 + c0);
        float4 wb = *(const float4*)(Wm + d * 72 + c0 + 4);
        float wv[8] = {wa.x, wa.y, wa.z, wa.w, wb.x, wb.y, wb.z, wb.w};
#pragma unroll
        for (int j = 0; j < 8; ++j) {
          unsigned short hi = f2bf(wv[j]);
          ((unsigned short*)&ah)[j] = hi;
          ((unsigned short*)&al)[j] = f2bf(wv[j] - bf2f(hi));
        }
      }
      acc[dm] = MFMA_BF16(ah, xbh[ks], acc[dm]);
      acc[dm] = MFMA_BF16(ah, xbl[ks], acc[dm]);
      acc[dm] = MFMA_BF16(al, xbh[ks], acc[dm]);
    }
  }

  if (m < 2) {
    // Q/K: bias + fp16, transpose via wave-private obuf (lgkmcnt only),
    // coalesced uint4 stores (cols 9..11 = zero pad)
    unsigned short* ob = obuf[ww];
#pragma unroll
    for (int dm = 0; dm < 5; ++dm)
#pragma unroll
      for (int r = 0; r < 4; ++r) {
        int d = dm * 16 + quad * 4 + r;
        float v = acc[dm][r] + (d < 72 ? bias[d] : 0.f);
        ob[l15 * XTS + d] = f2h(v);
      }
    unsigned short* outp = (m == 0) ? QH : KH;
    const size_t obase = ((size_t)b * NPIX + n0) * CP;
    uint4 z; z.x = z.y = z.z = z.w = 0u;
    for (int f = lane; f < 192; f += 64) {
      int row = f / 12, col = f % 12;
      *(uint4*)(outp + obase + (size_t)row * CP + col * 8) =
          (col < 10) ? *(const uint4*)(ob + row * XTS + col * 8) : z;
    }
  } else {
    // V: bias + bf16, store [c][n] direct; rows 72..79: ones-row + zeros
#pragma unroll
    for (int dm = 0; dm < 5; ++dm)
#pragma unroll
      for (int r = 0; r < 4; ++r) {
        int d = dm * 16 + quad * 4 + r;
        float v = (d < 72) ? acc[dm][r] + bias[d] : (d == 72 ? 1.0f : 0.f);
        VG[((size_t)b * 80 + d) * NPIX + n0 + l15] = f2bf(v);
      }
  }
}

// ---------------------------------------------------------------------------
// Kernel 2 (v9): flash + pooling + fused combine, ticket barrier with
// RMW-based polling.
// R8: acquire-per-poll -> device-wide invalidation storm (343us).
// R9: relaxed poll -> reads STALE local-L2 copy of `done` (per-XCD L2s not
//     cross-coherent; remote fetch_adds execute at the coherence point and
//     never invalidate the cached line) -> spin ends only on natural
//     eviction, ~100us late (177us).
// v9: poll with fetch_add(0) — an RMW always executes at the coherence
// point (required for cross-XCD atomicity), so it reads fresh data without
// invalidating anything. 64 pollers x 1 RMW / 0.4us sleep = negligible.
// Early-exit for the first FGRID-NCOMB tickets (no spin population, no
// co-residency assumption). One acquire fence after the spin invalidates
// stale NUM/LPART lines (addresses reused across graph replays).
// Flash compute core byte-identical to R5 (best measured 73.0us).
// ---------------------------------------------------------------------------
#define KCH 12    // K chunks per tile: (tj,ks) = 4x3
#define VCH 10    // V chunks per tile: (nt,js) = 5x2

__global__ __launch_bounds__(256, 3) void flash_kernel(
    const float* __restrict__ x,
    const unsigned short* __restrict__ QH, const unsigned short* __restrict__ KH,
    const unsigned short* __restrict__ VG,
    float* __restrict__ NUM, float* __restrict__ LPART,
    float* __restrict__ out, unsigned* done)
{
  __shared__ __align__(16) unsigned short ls_kh[KCH * 512];  // 12,288 B
  __shared__ __align__(16) unsigned short ls_vs[VCH * 512];  // 10,240 B
  __shared__ unsigned tkt;

  const int t    = threadIdx.x;
  const int w    = t >> 6;
  const int lane = t & 63;
  const int quad = lane >> 4;
  const int l15  = lane & 15;

  const int bid  = blockIdx.x;
  const int sp   = bid & 7;          // split == XCD id (round-robin dispatch)
  const int slot = bid >> 3;
  const int b    = slot / 48;
  const int it   = slot % 48;
  const int i0w  = it * 192 + w * 48;

  // Q fragments (B-operand of S^T scores: n=l15=i, k=quad*8+c)
  f16x8 qh[3][3];
#pragma unroll
  for (int mi = 0; mi < 3; ++mi)
#pragma unroll
    for (int ks = 0; ks < 3; ++ks) {
      size_t off = ((size_t)b * NPIX + i0w + mi * 16 + l15) * CP + ks * 32 + quad * 8;
      qh[mi][ks] = *(const f16x8*)(QH + off);
    }

  f32x4 oacc[3][5];   // O^T[c][i]: c = nt*16+quad*4+r, i = mi*16+l15
#pragma unroll
  for (int mi = 0; mi < 3; ++mi)
#pragma unroll
    for (int nt = 0; nt < 5; ++nt) oacc[mi][nt] = (f32x4){0.f, 0.f, 0.f, 0.f};

  const unsigned short* kpg = KH + ((size_t)b * NPIX + sp * JCHUNK) * CP;
  const unsigned short* vpg = VG + (size_t)b * 80 * NPIX + sp * JCHUNK;

  // per-lane gather source offsets (jt-invariant): this wave's chunks c=w+4k.
  int koff[3], voff[3];
#pragma unroll
  for (int k = 0; k < 3; ++k) {
    int c = w + 4 * k;
    koff[k] = ((c / 3) * 16 + l15) * CP + (c % 3) * 32 + quad * 8;
    int cv = (c < VCH) ? c : 0;
    voff[k] = ((cv >> 1) * 16 + l15) * NPIX + (cv & 1) * 32 + quad * 8;
  }

  for (int jt = 0; jt < JTILES; ++jt, kpg += 64 * CP, vpg += 64) {
    // ---- K tile: 12 fragment-order chunks via DMA (3 per wave) ----
#pragma unroll
    for (int k = 0; k < 3; ++k)
      load_lds16(kpg + koff[k], ls_kh + (w + 4 * k) * 512);
    // ---- V tile: 10 fragment-order chunks via DMA (2-3 per wave) ----
#pragma unroll
    for (int k = 0; k < 3; ++k)
      if (w + 4 * k < VCH)   // wave-uniform guard
        load_lds16(vpg + voff[k], ls_vs + (w + 4 * k) * 512);
    __syncthreads();   // drains vmcnt (all DMA) before LDS reads

#pragma unroll
    for (int js = 0; js < 2; ++js) {
      // ---- S^T for tj = js*2 (->pkA), js*2+1 (->pkB) ----
      uint2 pkA[3], pkB[3];
#pragma unroll
      for (int tjh = 0; tjh < 2; ++tjh) {
        const int tj = js * 2 + tjh;
        f16x8 fkh[3];
#pragma unroll
        for (int ks = 0; ks < 3; ++ks)
          fkh[ks] = *(const f16x8*)(ls_kh + (tj * 3 + ks) * 512 + lane * 8);
#pragma unroll
        for (int mi = 0; mi < 3; ++mi) {
          f32x4 s = (f32x4){0.f, 0.f, 0.f, 0.f};
          s = MFMA_F16(fkh[0], qh[mi][0], s);   // A=K (m=j), B=Q (n=i)
          s = MFMA_F16(fkh[1], qh[mi][1], s);
          s = MFMA_F16(fkh[2], qh[mi][2], s);
          float p0 = __builtin_amdgcn_exp2f(__builtin_fmaf(s[0], L2E, -EXPB));
          float p1 = __builtin_amdgcn_exp2f(__builtin_fmaf(s[1], L2E, -EXPB));
          float p2 = __builtin_amdgcn_exp2f(__builtin_fmaf(s[2], L2E, -EXPB));
          float p3 = __builtin_amdgcn_exp2f(__builtin_fmaf(s[3], L2E, -EXPB));
          uint2 pk;
          pk.x = pack_bf_trunc(p0, p1);
          pk.y = pack_bf_trunc(p2, p3);
          if (tjh == 0) pkA[mi] = pk; else pkB[mi] = pk;
        }
      }

      // ---- P redistribution in-register (validated R4/R5, conflicts=0) ----
      bf16x8 pf[3];
#pragma unroll
      for (int mi = 0; mi < 3; ++mi) {
        unsigned x0 = pkA[mi].x, x1 = pkB[mi].x;
        asm("v_permlane32_swap_b32 %0, %1" : "+v"(x0), "+v"(x1));
        asm("v_permlane16_swap_b32 %0, %1" : "+v"(x0), "+v"(x1));
        unsigned y0 = pkA[mi].y, y1 = pkB[mi].y;
        asm("v_permlane32_swap_b32 %0, %1" : "+v"(y0), "+v"(y1));
        asm("v_permlane16_swap_b32 %0, %1" : "+v"(y0), "+v"(y1));
        uint4 fr;
        fr.x = x0; fr.y = y0; fr.z = x1; fr.w = y1;
        pf[mi] = *(const bf16x8*)&fr;
      }

      // ---- PV half: A = V (m=c incl. ones-row 72), B = P (regs) ----
#pragma unroll
      for (int nt = 0; nt < 5; ++nt) {
        bf16x8 vf = *(const bf16x8*)(ls_vs + (nt * 2 + js) * 512 + lane * 8);
#pragma unroll
        for (int mi = 0; mi < 3; ++mi)
          oacc[mi][nt] = MFMA_BF16(vf, pf[mi], oacc[mi][nt]);
      }
    }
    __syncthreads();   // all K/V LDS reads done before next staging
  }

  // ---- epilogue: L from ones-row; fused factor-4 pooling -> NUM fp32 ----
  const size_t sb = (size_t)(sp * 2 + b);
#pragma unroll
  for (int mi = 0; mi < 3; ++mi) {
    const int i = i0w + mi * 16 + l15;
    if (quad == 2)   // c = 72: the ones-row -> L
      LPART[sb * NPIX + i] = oacc[mi][4][0];
#pragma unroll
    for (int nt = 0; nt < 5; ++nt) {
      int c0 = nt * 16 + quad * 4;
      if (c0 < 72) {
        float num = 0.f;
#pragma unroll
        for (int r = 0; r < 4; ++r)
          num = __builtin_fmaf(x[((size_t)b * CIN + c0 + r) * NPIX + i],
                               oacc[mi][nt][r], num);
        NUM[(sb * 18 + (c0 >> 2)) * NPIX + i] = num;   // g = nt*4+quad
      }
    }
  }

  // ---- ticket barrier: early blocks exit; last NCOMB arrivals combine ----
  __threadfence();                     // release: NUM/LPART -> coherent point
  __syncthreads();                     // every thread fenced before arrive
  if (t == 0)
    tkt = __hip_atomic_fetch_add(done, 1u, __ATOMIC_RELEASE,
                                 __HIP_MEMORY_SCOPE_AGENT);
  __syncthreads();
  const unsigned tk = tkt;
  if (tk < FGRID - NCOMB) return;      // free the CU; no spin population

  if (t == 0) {
    // Poll via RMW: always executes at the coherence point (fresh value),
    // no cache invalidation (unlike acquire loads), no staleness (unlike
    // relaxed loads hitting the non-coherent local L2).
    while (__hip_atomic_fetch_add(done, 0u, __ATOMIC_RELAXED,
                                  __HIP_MEMORY_SCOPE_AGENT) < FGRID)
      __builtin_amdgcn_s_sleep(16);    // ~0.4us between polls
  }
  __syncthreads();
  __threadfence();                     // acquire: invalidate stale lines once

  // ---- combine phase (last NCOMB blocks): out = sum(NUM)/sum(L) ----
  const int base = (int)(tk - (FGRID - NCOMB));
  for (int cid = base * 256 + t; cid < 2 * 18 * (NPIX / 4); cid += NCOMB * 256) {
    int n = (cid % (NPIX / 4)) * 4;
    int rest = cid / (NPIX / 4);       // = cb*18 + g
    int g = rest % 18, cb = rest / 18;
    float4 A = make_float4(0.f, 0.f, 0.f, 0.f);
    float4 L = make_float4(0.f, 0.f, 0.f, 0.f);
#pragma unroll
    for (int s = 0; s < SPLITS; ++s) {
      size_t sb2 = (size_t)(s * 2 + cb);
      float4 a = *(const float4*)(NUM + (sb2 * 18 + g) * NPIX + n);
      float4 l = *(const float4*)(LPART + sb2 * NPIX + n);
      A.x += a.x; A.y += a.y; A.z += a.z; A.w += a.w;
      L.x += l.x; L.y += l.y; L.z += l.z; L.w += l.w;
    }
    float4 r;
    r.x = A.x / L.x; r.y = A.y / L.y; r.z = A.z / L.z; r.w = A.w / L.w;
    *(float4*)(out + (size_t)cid * 4) = r;
  }
}

// ---------------------------------------------------------------------------
extern "C" void kernel_launch(void* const* d_in, const int* in_sizes, int n_in,
                              void* d_out, int out_size, void* d_ws, size_t ws_size,
                              hipStream_t stream) {
  const float* x  = (const float*)d_in[0];
  const float* Wq = (const float*)d_in[1];
  const float* bq = (const float*)d_in[2];
  const float* Wk = (const float*)d_in[3];
  const float* bk = (const float*)d_in[4];
  const float* Wv = (const float*)d_in[5];
  const float* bv = (const float*)d_in[6];
  float* out = (float*)d_out;

  char* p = (char*)d_ws;
  const size_t szQK = (size_t)2 * NPIX * CP * 2;
  unsigned short* QH = (unsigned short*)p; p += szQK;
  unsigned short* KH = (unsigned short*)p; p += szQK;
  unsigned short* VG = (unsigned short*)p; p += (size_t)2 * 80 * NPIX * 2;
  float* NUM = (float*)p; p += (size_t)SPLITS * 2 * 18 * NPIX * 4;   // 10.6 MB
  float* LPART = (float*)p; p += (size_t)SPLITS * 2 * NPIX * 4;      // 0.6 MB
  unsigned* done = (unsigned*)p; p += 64;                            // barrier ctr

  qkv_kernel<<<864, 256, 0, stream>>>(x, Wq, Wk, Wv, bq, bk, bv, QH, KH, VG, done);
  flash_kernel<<<FGRID, 256, 0, stream>>>(x, QH, KH, VG, NUM, LPART, out, done);
}

// Round 11
// 169.091 us; speedup vs baseline: 2.3162x; 1.4649x over previous
//
#include <hip/hip_runtime.h>

#define NPIX 9216
#define CIN 72
#define CP 96
#define SPLITS 8
#define JCHUNK (NPIX / SPLITS)   // 1152
#define JTILES (JCHUNK / 64)     // 18
#define FGRID (SPLITS * 2 * 48)  // flash grid = 768
#define NCOMB 64                 // last-arriving blocks that run combine
// p = exp2(s*log2e - 32*log2e)  (fixed softmax shift 32; safe to s<120)
#define L2E   1.44269504088896f
#define EXPB  46.1662413084468f

typedef __attribute__((ext_vector_type(8))) short bf16x8;
typedef __attribute__((ext_vector_type(8))) _Float16 f16x8;
typedef __attribute__((ext_vector_type(4))) float f32x4;

#define MFMA_BF16(A,B,C) __builtin_amdgcn_mfma_f32_16x16x32_bf16(A,B,C,0,0,0)
#define MFMA_F16(A,B,C)  __builtin_amdgcn_mfma_f32_16x16x32_f16(A,B,C,0,0,0)

static __device__ __forceinline__ unsigned short f2bf(float f) {
  unsigned u = __float_as_uint(f);
  u += 0x7fffu + ((u >> 16) & 1u);
  return (unsigned short)(u >> 16);
}
static __device__ __forceinline__ float bf2f(unsigned short h) {
  return __uint_as_float(((unsigned)h) << 16);
}
static __device__ __forceinline__ unsigned short f2h(float f) {
  _Float16 h = (_Float16)f;
  return *(unsigned short*)&h;
}
// pack trunc-bf16 of (lo,hi) into one dword: [lo.hi16 | hi.hi16]
static __device__ __forceinline__ unsigned pack_bf_trunc(float lo, float hi) {
  return (__float_as_uint(lo) >> 16) | (__float_as_uint(hi) & 0xffff0000u);
}
// async global->LDS DMA, 16B per lane; lds dest = uniform base + lane*16.
// global src is PER-LANE (m173): fragment-order LDS = per-lane gather src.
static __device__ __forceinline__ void load_lds16(const void* g, void* l) {
  __builtin_amdgcn_global_load_lds(
      (const __attribute__((address_space(1))) unsigned int*)g,
      (__attribute__((address_space(3))) unsigned int*)l, 16, 0, 0);
}

// ---------------------------------------------------------------------------
// Kernel 1 (v5): QKV projection — fully-decoupled waves, wprep fused
// (validated R8/R9/R10). Resets the flash ticket counter (stream order).
// ---------------------------------------------------------------------------
#define XTS 104   // obuf row stride (ushorts), 208 B

__global__ __launch_bounds__(256) void qkv_kernel(
    const float* __restrict__ x,
    const float* __restrict__ Wq, const float* __restrict__ Wk,
    const float* __restrict__ Wv,
    const float* __restrict__ bq, const float* __restrict__ bk,
    const float* __restrict__ bv,
    unsigned short* __restrict__ QH, unsigned short* __restrict__ KH,
    unsigned short* __restrict__ VG, unsigned* done)
{
  __shared__ __align__(16) unsigned short obuf[4][16 * XTS];  // 13,312 B

  const int t    = threadIdx.x;
  const int ww   = t >> 6;
  const int lane = t & 63;
  const int quad = lane >> 4;
  const int l15  = lane & 15;

  if (blockIdx.x == 0 && t == 0)
    __hip_atomic_store(done, 0u, __ATOMIC_RELAXED, __HIP_MEMORY_SCOPE_AGENT);

  const int task  = blockIdx.x * 4 + ww;   // 0..3455
  const int m     = task % 3;              // 0=Q, 1=K, 2=V
  const int strip = task / 3;              // 0..1151
  const int b     = strip / 576;
  const int n0    = (strip % 576) * 16;

  // ---- X B-frags direct from global (n = l15 = px, k = quad*8+j) ----
  bf16x8 xbh[3], xbl[3];
#pragma unroll
  for (int ks = 0; ks < 3; ++ks) {
#pragma unroll
    for (int j = 0; j < 8; ++j) {
      int c = ks * 32 + quad * 8 + j;
      c = (c < 72) ? c : 71;               // clamp: W cols >=72 are zero
      float v = x[((size_t)b * CIN + c) * NPIX + n0 + l15];
      unsigned short hi = f2bf(v);
      ((unsigned short*)&xbh[ks])[j] = hi;
      ((unsigned short*)&xbl[ks])[j] = f2bf(v - bf2f(hi));
    }
  }

  const float* Wm   = (m == 0) ? Wq : (m == 1) ? Wk : Wv;
  const float* bias = (m == 0) ? bq : (m == 1) ? bk : bv;

  // ---- split-bf16 MFMA; W fragments converted inline from float ----
  f32x4 acc[5];
#pragma unroll
  for (int dm = 0; dm < 5; ++dm) {
    acc[dm] = (f32x4){0.f, 0.f, 0.f, 0.f};
    const int d = dm * 16 + l15;
#pragma unroll
    for (int ks = 0; ks < 3; ++ks) {
      const int c0 = ks * 32 + quad * 8;
      bf16x8 ah = (bf16x8)(short)0, al = (bf16x8)(short)0;
      if (d < 72 && c0 < 72) {             // pad region -> zeros (== old WH/WL)
        float4 wa = *(const float4*)(Wm + d * 72 + c0);
        float4 wb = *(const float4*)(Wm + d * 72 + c0 + 4);
        float wv[8] = {wa.x, wa.y, wa.z, wa.w, wb.x, wb.y, wb.z, wb.w};
#pragma unroll
        for (int j = 0; j < 8; ++j) {
          unsigned short hi = f2bf(wv[j]);
          ((unsigned short*)&ah)[j] = hi;
          ((unsigned short*)&al)[j] = f2bf(wv[j] - bf2f(hi));
        }
      }
      acc[dm] = MFMA_BF16(ah, xbh[ks], acc[dm]);
      acc[dm] = MFMA_BF16(ah, xbl[ks], acc[dm]);
      acc[dm] = MFMA_BF16(al, xbh[ks], acc[dm]);
    }
  }

  if (m < 2) {
    // Q/K: bias + fp16, transpose via wave-private obuf (lgkmcnt only),
    // coalesced uint4 stores (cols 9..11 = zero pad)
    unsigned short* ob = obuf[ww];
#pragma unroll
    for (int dm = 0; dm < 5; ++dm)
#pragma unroll
      for (int r = 0; r < 4; ++r) {
        int d = dm * 16 + quad * 4 + r;
        float v = acc[dm][r] + (d < 72 ? bias[d] : 0.f);
        ob[l15 * XTS + d] = f2h(v);
      }
    unsigned short* outp = (m == 0) ? QH : KH;
    const size_t obase = ((size_t)b * NPIX + n0) * CP;
    uint4 z; z.x = z.y = z.z = z.w = 0u;
    for (int f = lane; f < 192; f += 64) {
      int row = f / 12, col = f % 12;
      *(uint4*)(outp + obase + (size_t)row * CP + col * 8) =
          (col < 10) ? *(const uint4*)(ob + row * XTS + col * 8) : z;
    }
  } else {
    // V: bias + bf16, store [c][n] direct; rows 72..79: ones-row + zeros
#pragma unroll
    for (int dm = 0; dm < 5; ++dm)
#pragma unroll
      for (int r = 0; r < 4; ++r) {
        int d = dm * 16 + quad * 4 + r;
        float v = (d < 72) ? acc[dm][r] + bias[d] : (d == 72 ? 1.0f : 0.f);
        VG[((size_t)b * 80 + d) * NPIX + n0 + l15] = f2bf(v);
      }
  }
}

// ---------------------------------------------------------------------------
// Kernel 2 (v10): flash + pooling + fused combine — MINIMAL-FENCE barrier.
// R10 post-mortem: poll flavor irrelevant (R9==R10==177us). Counter algebra
// (MFMA/VALU cycles conserved, occupancy 25.6->21.2) shows COMPUTE itself
// stretched 73->~144us at full residency. Cause: __threadfence() = seq_cst
// agent fence = buffer_wbl2 + BUFFER_INV -> each of 768 finishing blocks
// invalidated its XCD's entire L2 while the rest still computed, destroying
// the KH/VG L2 reuse (96 blocks/XCD re-read the same 1.3MB slice ~48x).
// R8's per-poll acquire was the same disease amplified.
// v10 fences exactly per the memory model:
//  * arrival: fetch_add RELEASE only -> buffer_wbl2 (write back dirty, NO
//    invalidate; clean KH/VG lines survive). __syncthreads() before it has
//    already drained all the block's stores (vmcnt(0)).
//  * poll: RMW RELAXED (coherence-point read, no fence codegen).
//  * acquire: ONE __builtin_amdgcn_fence(ACQUIRE, agent) = buffer_inv, in
//    the 64 combine blocks only, AFTER the spin — no compute left to hurt.
// Flash compute core byte-identical to R5 (best measured 73.0us).
// ---------------------------------------------------------------------------
#define KCH 12    // K chunks per tile: (tj,ks) = 4x3
#define VCH 10    // V chunks per tile: (nt,js) = 5x2

__global__ __launch_bounds__(256, 3) void flash_kernel(
    const float* __restrict__ x,
    const unsigned short* __restrict__ QH, const unsigned short* __restrict__ KH,
    const unsigned short* __restrict__ VG,
    float* __restrict__ NUM, float* __restrict__ LPART,
    float* __restrict__ out, unsigned* done)
{
  __shared__ __align__(16) unsigned short ls_kh[KCH * 512];  // 12,288 B
  __shared__ __align__(16) unsigned short ls_vs[VCH * 512];  // 10,240 B
  __shared__ unsigned tkt;

  const int t    = threadIdx.x;
  const int w    = t >> 6;
  const int lane = t & 63;
  const int quad = lane >> 4;
  const int l15  = lane & 15;

  const int bid  = blockIdx.x;
  const int sp   = bid & 7;          // split == XCD id (round-robin dispatch)
  const int slot = bid >> 3;
  const int b    = slot / 48;
  const int it   = slot % 48;
  const int i0w  = it * 192 + w * 48;

  // Q fragments (B-operand of S^T scores: n=l15=i, k=quad*8+c)
  f16x8 qh[3][3];
#pragma unroll
  for (int mi = 0; mi < 3; ++mi)
#pragma unroll
    for (int ks = 0; ks < 3; ++ks) {
      size_t off = ((size_t)b * NPIX + i0w + mi * 16 + l15) * CP + ks * 32 + quad * 8;
      qh[mi][ks] = *(const f16x8*)(QH + off);
    }

  f32x4 oacc[3][5];   // O^T[c][i]: c = nt*16+quad*4+r, i = mi*16+l15
#pragma unroll
  for (int mi = 0; mi < 3; ++mi)
#pragma unroll
    for (int nt = 0; nt < 5; ++nt) oacc[mi][nt] = (f32x4){0.f, 0.f, 0.f, 0.f};

  const unsigned short* kpg = KH + ((size_t)b * NPIX + sp * JCHUNK) * CP;
  const unsigned short* vpg = VG + (size_t)b * 80 * NPIX + sp * JCHUNK;

  // per-lane gather source offsets (jt-invariant): this wave's chunks c=w+4k.
  int koff[3], voff[3];
#pragma unroll
  for (int k = 0; k < 3; ++k) {
    int c = w + 4 * k;
    koff[k] = ((c / 3) * 16 + l15) * CP + (c % 3) * 32 + quad * 8;
    int cv = (c < VCH) ? c : 0;
    voff[k] = ((cv >> 1) * 16 + l15) * NPIX + (cv & 1) * 32 + quad * 8;
  }

  for (int jt = 0; jt < JTILES; ++jt, kpg += 64 * CP, vpg += 64) {
    // ---- K tile: 12 fragment-order chunks via DMA (3 per wave) ----
#pragma unroll
    for (int k = 0; k < 3; ++k)
      load_lds16(kpg + koff[k], ls_kh + (w + 4 * k) * 512);
    // ---- V tile: 10 fragment-order chunks via DMA (2-3 per wave) ----
#pragma unroll
    for (int k = 0; k < 3; ++k)
      if (w + 4 * k < VCH)   // wave-uniform guard
        load_lds16(vpg + voff[k], ls_vs + (w + 4 * k) * 512);
    __syncthreads();   // drains vmcnt (all DMA) before LDS reads

#pragma unroll
    for (int js = 0; js < 2; ++js) {
      // ---- S^T for tj = js*2 (->pkA), js*2+1 (->pkB) ----
      uint2 pkA[3], pkB[3];
#pragma unroll
      for (int tjh = 0; tjh < 2; ++tjh) {
        const int tj = js * 2 + tjh;
        f16x8 fkh[3];
#pragma unroll
        for (int ks = 0; ks < 3; ++ks)
          fkh[ks] = *(const f16x8*)(ls_kh + (tj * 3 + ks) * 512 + lane * 8);
#pragma unroll
        for (int mi = 0; mi < 3; ++mi) {
          f32x4 s = (f32x4){0.f, 0.f, 0.f, 0.f};
          s = MFMA_F16(fkh[0], qh[mi][0], s);   // A=K (m=j), B=Q (n=i)
          s = MFMA_F16(fkh[1], qh[mi][1], s);
          s = MFMA_F16(fkh[2], qh[mi][2], s);
          float p0 = __builtin_amdgcn_exp2f(__builtin_fmaf(s[0], L2E, -EXPB));
          float p1 = __builtin_amdgcn_exp2f(__builtin_fmaf(s[1], L2E, -EXPB));
          float p2 = __builtin_amdgcn_exp2f(__builtin_fmaf(s[2], L2E, -EXPB));
          float p3 = __builtin_amdgcn_exp2f(__builtin_fmaf(s[3], L2E, -EXPB));
          uint2 pk;
          pk.x = pack_bf_trunc(p0, p1);
          pk.y = pack_bf_trunc(p2, p3);
          if (tjh == 0) pkA[mi] = pk; else pkB[mi] = pk;
        }
      }

      // ---- P redistribution in-register (validated R4/R5, conflicts=0) ----
      bf16x8 pf[3];
#pragma unroll
      for (int mi = 0; mi < 3; ++mi) {
        unsigned x0 = pkA[mi].x, x1 = pkB[mi].x;
        asm("v_permlane32_swap_b32 %0, %1" : "+v"(x0), "+v"(x1));
        asm("v_permlane16_swap_b32 %0, %1" : "+v"(x0), "+v"(x1));
        unsigned y0 = pkA[mi].y, y1 = pkB[mi].y;
        asm("v_permlane32_swap_b32 %0, %1" : "+v"(y0), "+v"(y1));
        asm("v_permlane16_swap_b32 %0, %1" : "+v"(y0), "+v"(y1));
        uint4 fr;
        fr.x = x0; fr.y = y0; fr.z = x1; fr.w = y1;
        pf[mi] = *(const bf16x8*)&fr;
      }

      // ---- PV half: A = V (m=c incl. ones-row 72), B = P (regs) ----
#pragma unroll
      for (int nt = 0; nt < 5; ++nt) {
        bf16x8 vf = *(const bf16x8*)(ls_vs + (nt * 2 + js) * 512 + lane * 8);
#pragma unroll
        for (int mi = 0; mi < 3; ++mi)
          oacc[mi][nt] = MFMA_BF16(vf, pf[mi], oacc[mi][nt]);
      }
    }
    __syncthreads();   // all K/V LDS reads done before next staging
  }

  // ---- epilogue: L from ones-row; fused factor-4 pooling -> NUM fp32 ----
  const size_t sb = (size_t)(sp * 2 + b);
#pragma unroll
  for (int mi = 0; mi < 3; ++mi) {
    const int i = i0w + mi * 16 + l15;
    if (quad == 2)   // c = 72: the ones-row -> L
      LPART[sb * NPIX + i] = oacc[mi][4][0];
#pragma unroll
    for (int nt = 0; nt < 5; ++nt) {
      int c0 = nt * 16 + quad * 4;
      if (c0 < 72) {
        float num = 0.f;
#pragma unroll
        for (int r = 0; r < 4; ++r)
          num = __builtin_fmaf(x[((size_t)b * CIN + c0 + r) * NPIX + i],
                               oacc[mi][nt][r], num);
        NUM[(sb * 18 + (c0 >> 2)) * NPIX + i] = num;   // g = nt*4+quad
      }
    }
  }

  // ---- ticket barrier, minimal fences ----
  // __syncthreads() drains every thread's NUM/LPART stores (vmcnt(0) before
  // s_barrier), then t0's RELEASE RMW emits buffer_wbl2 (writeback only, NO
  // L2 invalidate) before the atomic -> the block's writes are visible at
  // the coherence point without nuking other blocks' L2 reuse.
  __syncthreads();
  if (t == 0)
    tkt = __hip_atomic_fetch_add(done, 1u, __ATOMIC_RELEASE,
                                 __HIP_MEMORY_SCOPE_AGENT);
  __syncthreads();
  const unsigned tk = tkt;
  if (tk < FGRID - NCOMB) return;      // free the CU; no fence on exit path

  if (t == 0) {
    // RELAXED RMW poll: executes at the coherence point (fresh value),
    // emits no cache-maintenance ops.
    while (__hip_atomic_fetch_add(done, 0u, __ATOMIC_RELAXED,
                                  __HIP_MEMORY_SCOPE_AGENT) < FGRID)
      __builtin_amdgcn_s_sleep(16);    // ~0.4us between polls
  }
  __syncthreads();
  // Single acquire fence (buffer_inv) per combine block, AFTER all compute
  // on the device is done — invalidates stale NUM/LPART lines exactly once.
  __builtin_amdgcn_fence(__ATOMIC_ACQUIRE, "agent");

  // ---- combine phase (last NCOMB blocks): out = sum(NUM)/sum(L) ----
  const int base = (int)(tk - (FGRID - NCOMB));
  for (int cid = base * 256 + t; cid < 2 * 18 * (NPIX / 4); cid += NCOMB * 256) {
    int n = (cid % (NPIX / 4)) * 4;
    int rest = cid / (NPIX / 4);       // = cb*18 + g
    int g = rest % 18, cb = rest / 18;
    float4 A = make_float4(0.f, 0.f, 0.f, 0.f);
    float4 L = make_float4(0.f, 0.f, 0.f, 0.f);
#pragma unroll
    for (int s = 0; s < SPLITS; ++s) {
      size_t sb2 = (size_t)(s * 2 + cb);
      float4 a = *(const float4*)(NUM + (sb2 * 18 + g) * NPIX + n);
      float4 l = *(const float4*)(LPART + sb2 * NPIX + n);
      A.x += a.x; A.y += a.y; A.z += a.z; A.w += a.w;
      L.x += l.x; L.y += l.y; L.z += l.z; L.w += l.w;
    }
    float4 r;
    r.x = A.x / L.x; r.y = A.y / L.y; r.z = A.z / L.z; r.w = A.w / L.w;
    *(float4*)(out + (size_t)cid * 4) = r;
  }
}

// ---------------------------------------------------------------------------
extern "C" void kernel_launch(void* const* d_in, const int* in_sizes, int n_in,
                              void* d_out, int out_size, void* d_ws, size_t ws_size,
                              hipStream_t stream) {
  const float* x  = (const float*)d_in[0];
  const float* Wq = (const float*)d_in[1];
  const float* bq = (const float*)d_in[2];
  const float* Wk = (const float*)d_in[3];
  const float* bk = (const float*)d_in[4];
  const float* Wv = (const float*)d_in[5];
  const float* bv = (const float*)d_in[6];
  float* out = (float*)d_out;

  char* p = (char*)d_ws;
  const size_t szQK = (size_t)2 * NPIX * CP * 2;
  unsigned short* QH = (unsigned short*)p; p += szQK;
  unsigned short* KH = (unsigned short*)p; p += szQK;
  unsigned short* VG = (unsigned short*)p; p += (size_t)2 * 80 * NPIX * 2;
  float* NUM = (float*)p; p += (size_t)SPLITS * 2 * 18 * NPIX * 4;   // 10.6 MB
  float* LPART = (float*)p; p += (size_t)SPLITS * 2 * NPIX * 4;      // 0.6 MB
  unsigned* done = (unsigned*)p; p += 64;                            // barrier ctr

  qkv_kernel<<<864, 256, 0, stream>>>(x, Wq, Wk, Wv, bq, bk, bv, QH, KH, VG, done);
  flash_kernel<<<FGRID, 256, 0, stream>>>(x, QH, KH, VG, NUM, LPART, out, done);
}

// Round 12
// 146.063 us; speedup vs baseline: 2.6814x; 1.1577x over previous
//
#include <hip/hip_runtime.h>

#define NPIX 9216
#define CIN 72
#define CP 96
#define SPLITS 8
#define JCHUNK (NPIX / SPLITS)   // 1152
#define JTILES (JCHUNK / 64)     // 18
#define FGRID (SPLITS * 2 * 48)  // flash grid = 768
// p = exp2(s*log2e - 32*log2e)  (fixed softmax shift 32; safe to s<120)
#define L2E   1.44269504088896f
#define EXPB  46.1662413084468f

typedef __attribute__((ext_vector_type(8))) short bf16x8;
typedef __attribute__((ext_vector_type(8))) _Float16 f16x8;
typedef __attribute__((ext_vector_type(4))) float f32x4;

#define MFMA_BF16(A,B,C) __builtin_amdgcn_mfma_f32_16x16x32_bf16(A,B,C,0,0,0)
#define MFMA_F16(A,B,C)  __builtin_amdgcn_mfma_f32_16x16x32_f16(A,B,C,0,0,0)

static __device__ __forceinline__ unsigned short f2bf(float f) {
  unsigned u = __float_as_uint(f);
  u += 0x7fffu + ((u >> 16) & 1u);
  return (unsigned short)(u >> 16);
}
static __device__ __forceinline__ float bf2f(unsigned short h) {
  return __uint_as_float(((unsigned)h) << 16);
}
static __device__ __forceinline__ unsigned short f2h(float f) {
  _Float16 h = (_Float16)f;
  return *(unsigned short*)&h;
}
// pack trunc-bf16 of (lo,hi) into one dword: [lo.hi16 | hi.hi16]
static __device__ __forceinline__ unsigned pack_bf_trunc(float lo, float hi) {
  return (__float_as_uint(lo) >> 16) | (__float_as_uint(hi) & 0xffff0000u);
}
// async global->LDS DMA, 16B per lane; lds dest = uniform base + lane*16.
// global src is PER-LANE (m173): fragment-order LDS = per-lane gather src.
static __device__ __forceinline__ void load_lds16(const void* g, void* l) {
  __builtin_amdgcn_global_load_lds(
      (const __attribute__((address_space(1))) unsigned int*)g,
      (__attribute__((address_space(3))) unsigned int*)l, 16, 0, 0);
}

// ---------------------------------------------------------------------------
// Kernel 1 (v5): QKV projection — fully-decoupled waves, wprep fused.
// Validated 4x (R8-R11, passed, absmax unchanged). Each wave = one
// (matrix, 16-px strip); no barriers; W split-bf16 converted inline from
// raw float W (bit-identical to the old wprep path). ~5us by construction
// (R7/R11 residual algebra).
// ---------------------------------------------------------------------------
#define XTS 104   // obuf row stride (ushorts), 208 B

__global__ __launch_bounds__(256) void qkv_kernel(
    const float* __restrict__ x,
    const float* __restrict__ Wq, const float* __restrict__ Wk,
    const float* __restrict__ Wv,
    const float* __restrict__ bq, const float* __restrict__ bk,
    const float* __restrict__ bv,
    unsigned short* __restrict__ QH, unsigned short* __restrict__ KH,
    unsigned short* __restrict__ VG)
{
  __shared__ __align__(16) unsigned short obuf[4][16 * XTS];  // 13,312 B

  const int t    = threadIdx.x;
  const int ww   = t >> 6;
  const int lane = t & 63;
  const int quad = lane >> 4;
  const int l15  = lane & 15;

  const int task  = blockIdx.x * 4 + ww;   // 0..3455
  const int m     = task % 3;              // 0=Q, 1=K, 2=V
  const int strip = task / 3;              // 0..1151
  const int b     = strip / 576;
  const int n0    = (strip % 576) * 16;

  // ---- X B-frags direct from global (n = l15 = px, k = quad*8+j) ----
  bf16x8 xbh[3], xbl[3];
#pragma unroll
  for (int ks = 0; ks < 3; ++ks) {
#pragma unroll
    for (int j = 0; j < 8; ++j) {
      int c = ks * 32 + quad * 8 + j;
      c = (c < 72) ? c : 71;               // clamp: W cols >=72 are zero
      float v = x[((size_t)b * CIN + c) * NPIX + n0 + l15];
      unsigned short hi = f2bf(v);
      ((unsigned short*)&xbh[ks])[j] = hi;
      ((unsigned short*)&xbl[ks])[j] = f2bf(v - bf2f(hi));
    }
  }

  const float* Wm   = (m == 0) ? Wq : (m == 1) ? Wk : Wv;
  const float* bias = (m == 0) ? bq : (m == 1) ? bk : bv;

  // ---- split-bf16 MFMA; W fragments converted inline from float ----
  f32x4 acc[5];
#pragma unroll
  for (int dm = 0; dm < 5; ++dm) {
    acc[dm] = (f32x4){0.f, 0.f, 0.f, 0.f};
    const int d = dm * 16 + l15;
#pragma unroll
    for (int ks = 0; ks < 3; ++ks) {
      const int c0 = ks * 32 + quad * 8;
      bf16x8 ah = (bf16x8)(short)0, al = (bf16x8)(short)0;
      if (d < 72 && c0 < 72) {             // pad region -> zeros (== old WH/WL)
        float4 wa = *(const float4*)(Wm + d * 72 + c0);
        float4 wb = *(const float4*)(Wm + d * 72 + c0 + 4);
        float wv[8] = {wa.x, wa.y, wa.z, wa.w, wb.x, wb.y, wb.z, wb.w};
#pragma unroll
        for (int j = 0; j < 8; ++j) {
          unsigned short hi = f2bf(wv[j]);
          ((unsigned short*)&ah)[j] = hi;
          ((unsigned short*)&al)[j] = f2bf(wv[j] - bf2f(hi));
        }
      }
      acc[dm] = MFMA_BF16(ah, xbh[ks], acc[dm]);
      acc[dm] = MFMA_BF16(ah, xbl[ks], acc[dm]);
      acc[dm] = MFMA_BF16(al, xbh[ks], acc[dm]);
    }
  }

  if (m < 2) {
    // Q/K: bias + fp16, transpose via wave-private obuf (lgkmcnt only),
    // coalesced uint4 stores (cols 9..11 = zero pad)
    unsigned short* ob = obuf[ww];
#pragma unroll
    for (int dm = 0; dm < 5; ++dm)
#pragma unroll
      for (int r = 0; r < 4; ++r) {
        int d = dm * 16 + quad * 4 + r;
        float v = acc[dm][r] + (d < 72 ? bias[d] : 0.f);
        ob[l15 * XTS + d] = f2h(v);
      }
    unsigned short* outp = (m == 0) ? QH : KH;
    const size_t obase = ((size_t)b * NPIX + n0) * CP;
    uint4 z; z.x = z.y = z.z = z.w = 0u;
    for (int f = lane; f < 192; f += 64) {
      int row = f / 12, col = f % 12;
      *(uint4*)(outp + obase + (size_t)row * CP + col * 8) =
          (col < 10) ? *(const uint4*)(ob + row * XTS + col * 8) : z;
    }
  } else {
    // V: bias + bf16, store [c][n] direct; rows 72..79: ones-row + zeros
#pragma unroll
    for (int dm = 0; dm < 5; ++dm)
#pragma unroll
      for (int r = 0; r < 4; ++r) {
        int d = dm * 16 + quad * 4 + r;
        float v = (d < 72) ? acc[dm][r] + bias[d] : (d == 72 ? 1.0f : 0.f);
        VG[((size_t)b * 80 + d) * NPIX + n0 + l15] = f2bf(v);
      }
  }
}

// ---------------------------------------------------------------------------
// Kernel 2 (v11): flash attention + pooling — R5 core (best measured 73.0us)
// + T5 s_setprio around the MFMA clusters. No grid barrier (R8-R11 arc:
// every in-kernel sync variant cost >= its savings; condemned).
// setprio regime check (m190/m191): helps when waves on a CU are at
// DIFFERENT phases (attn-like; here 3 independent blocks/CU), not lockstep.
// ---------------------------------------------------------------------------
#define KCH 12    // K chunks per tile: (tj,ks) = 4x3
#define VCH 10    // V chunks per tile: (nt,js) = 5x2

__global__ __launch_bounds__(256, 3) void flash_kernel(
    const float* __restrict__ x,
    const unsigned short* __restrict__ QH, const unsigned short* __restrict__ KH,
    const unsigned short* __restrict__ VG,
    float* __restrict__ NUM, float* __restrict__ LPART)
{
  __shared__ __align__(16) unsigned short ls_kh[KCH * 512];  // 12,288 B
  __shared__ __align__(16) unsigned short ls_vs[VCH * 512];  // 10,240 B

  const int t    = threadIdx.x;
  const int w    = t >> 6;
  const int lane = t & 63;
  const int quad = lane >> 4;
  const int l15  = lane & 15;

  const int bid  = blockIdx.x;
  const int sp   = bid & 7;          // split == XCD id (round-robin dispatch)
  const int slot = bid >> 3;
  const int b    = slot / 48;
  const int it   = slot % 48;
  const int i0w  = it * 192 + w * 48;

  // Q fragments (B-operand of S^T scores: n=l15=i, k=quad*8+c)
  f16x8 qh[3][3];
#pragma unroll
  for (int mi = 0; mi < 3; ++mi)
#pragma unroll
    for (int ks = 0; ks < 3; ++ks) {
      size_t off = ((size_t)b * NPIX + i0w + mi * 16 + l15) * CP + ks * 32 + quad * 8;
      qh[mi][ks] = *(const f16x8*)(QH + off);
    }

  f32x4 oacc[3][5];   // O^T[c][i]: c = nt*16+quad*4+r, i = mi*16+l15
#pragma unroll
  for (int mi = 0; mi < 3; ++mi)
#pragma unroll
    for (int nt = 0; nt < 5; ++nt) oacc[mi][nt] = (f32x4){0.f, 0.f, 0.f, 0.f};

  const unsigned short* kpg = KH + ((size_t)b * NPIX + sp * JCHUNK) * CP;
  const unsigned short* vpg = VG + (size_t)b * 80 * NPIX + sp * JCHUNK;

  // per-lane gather source offsets (jt-invariant): this wave's chunks c=w+4k.
  int koff[3], voff[3];
#pragma unroll
  for (int k = 0; k < 3; ++k) {
    int c = w + 4 * k;
    koff[k] = ((c / 3) * 16 + l15) * CP + (c % 3) * 32 + quad * 8;
    int cv = (c < VCH) ? c : 0;
    voff[k] = ((cv >> 1) * 16 + l15) * NPIX + (cv & 1) * 32 + quad * 8;
  }

  for (int jt = 0; jt < JTILES; ++jt, kpg += 64 * CP, vpg += 64) {
    // ---- K tile: 12 fragment-order chunks via DMA (3 per wave) ----
#pragma unroll
    for (int k = 0; k < 3; ++k)
      load_lds16(kpg + koff[k], ls_kh + (w + 4 * k) * 512);
    // ---- V tile: 10 fragment-order chunks via DMA (2-3 per wave) ----
#pragma unroll
    for (int k = 0; k < 3; ++k)
      if (w + 4 * k < VCH)   // wave-uniform guard
        load_lds16(vpg + voff[k], ls_vs + (w + 4 * k) * 512);
    __syncthreads();   // drains vmcnt (all DMA) before LDS reads

#pragma unroll
    for (int js = 0; js < 2; ++js) {
      // ---- S^T for tj = js*2 (->pkA), js*2+1 (->pkB) ----
      uint2 pkA[3], pkB[3];
#pragma unroll
      for (int tjh = 0; tjh < 2; ++tjh) {
        const int tj = js * 2 + tjh;
        f16x8 fkh[3];
#pragma unroll
        for (int ks = 0; ks < 3; ++ks)
          fkh[ks] = *(const f16x8*)(ls_kh + (tj * 3 + ks) * 512 + lane * 8);
#pragma unroll
        for (int mi = 0; mi < 3; ++mi) {
          f32x4 s = (f32x4){0.f, 0.f, 0.f, 0.f};
          __builtin_amdgcn_s_setprio(1);
          s = MFMA_F16(fkh[0], qh[mi][0], s);   // A=K (m=j), B=Q (n=i)
          s = MFMA_F16(fkh[1], qh[mi][1], s);
          s = MFMA_F16(fkh[2], qh[mi][2], s);
          __builtin_amdgcn_s_setprio(0);
          float p0 = __builtin_amdgcn_exp2f(__builtin_fmaf(s[0], L2E, -EXPB));
          float p1 = __builtin_amdgcn_exp2f(__builtin_fmaf(s[1], L2E, -EXPB));
          float p2 = __builtin_amdgcn_exp2f(__builtin_fmaf(s[2], L2E, -EXPB));
          float p3 = __builtin_amdgcn_exp2f(__builtin_fmaf(s[3], L2E, -EXPB));
          uint2 pk;
          pk.x = pack_bf_trunc(p0, p1);
          pk.y = pack_bf_trunc(p2, p3);
          if (tjh == 0) pkA[mi] = pk; else pkB[mi] = pk;
        }
      }

      // ---- P redistribution in-register (validated R4/R5, conflicts=0) ----
      bf16x8 pf[3];
#pragma unroll
      for (int mi = 0; mi < 3; ++mi) {
        unsigned x0 = pkA[mi].x, x1 = pkB[mi].x;
        asm("v_permlane32_swap_b32 %0, %1" : "+v"(x0), "+v"(x1));
        asm("v_permlane16_swap_b32 %0, %1" : "+v"(x0), "+v"(x1));
        unsigned y0 = pkA[mi].y, y1 = pkB[mi].y;
        asm("v_permlane32_swap_b32 %0, %1" : "+v"(y0), "+v"(y1));
        asm("v_permlane16_swap_b32 %0, %1" : "+v"(y0), "+v"(y1));
        uint4 fr;
        fr.x = x0; fr.y = y0; fr.z = x1; fr.w = y1;
        pf[mi] = *(const bf16x8*)&fr;
      }

      // ---- PV half: A = V (m=c incl. ones-row 72), B = P (regs) ----
#pragma unroll
      for (int nt = 0; nt < 5; ++nt) {
        bf16x8 vf = *(const bf16x8*)(ls_vs + (nt * 2 + js) * 512 + lane * 8);
        __builtin_amdgcn_s_setprio(1);
#pragma unroll
        for (int mi = 0; mi < 3; ++mi)
          oacc[mi][nt] = MFMA_BF16(vf, pf[mi], oacc[mi][nt]);
        __builtin_amdgcn_s_setprio(0);
      }
    }
    __syncthreads();   // all K/V LDS reads done before next staging
  }

  // ---- epilogue: L from ones-row; fused factor-4 pooling -> NUM fp32 ----
  const size_t sb = (size_t)(sp * 2 + b);
#pragma unroll
  for (int mi = 0; mi < 3; ++mi) {
    const int i = i0w + mi * 16 + l15;
    if (quad == 2)   // c = 72: the ones-row -> L
      LPART[sb * NPIX + i] = oacc[mi][4][0];
#pragma unroll
    for (int nt = 0; nt < 5; ++nt) {
      int c0 = nt * 16 + quad * 4;
      if (c0 < 72) {
        float num = 0.f;
#pragma unroll
        for (int r = 0; r < 4; ++r)
          num = __builtin_fmaf(x[((size_t)b * CIN + c0 + r) * NPIX + i],
                               oacc[mi][nt][r], num);
        NUM[(sb * 18 + (c0 >> 2)) * NPIX + i] = num;   // g = nt*4+quad
      }
    }
  }
}

// ---------------------------------------------------------------------------
// Kernel 3: combine splits: out = (sum_s NUM_s) / (sum_s L_s). Trivial.
// ---------------------------------------------------------------------------
__global__ __launch_bounds__(256) void combine_pool_kernel(
    const float* __restrict__ NUM, const float* __restrict__ LPART,
    float* __restrict__ out)
{
  int id = blockIdx.x * 256 + threadIdx.x;
  if (id >= 2 * 18 * (NPIX / 4)) return;
  int n = (id % (NPIX / 4)) * 4;
  int rest = id / (NPIX / 4);       // = b*18 + g
  int g = rest % 18, b = rest / 18;

  float4 A = make_float4(0.f, 0.f, 0.f, 0.f);
  float4 L = make_float4(0.f, 0.f, 0.f, 0.f);
#pragma unroll
  for (int s = 0; s < SPLITS; ++s) {
    size_t sb = (size_t)(s * 2 + b);
    float4 a = *(const float4*)(NUM + (sb * 18 + g) * NPIX + n);
    float4 l = *(const float4*)(LPART + sb * NPIX + n);
    A.x += a.x; A.y += a.y; A.z += a.z; A.w += a.w;
    L.x += l.x; L.y += l.y; L.z += l.z; L.w += l.w;
  }
  float4 r;
  r.x = A.x / L.x; r.y = A.y / L.y; r.z = A.z / L.z; r.w = A.w / L.w;
  *(float4*)(out + (size_t)id * 4) = r;
}

// ---------------------------------------------------------------------------
extern "C" void kernel_launch(void* const* d_in, const int* in_sizes, int n_in,
                              void* d_out, int out_size, void* d_ws, size_t ws_size,
                              hipStream_t stream) {
  const float* x  = (const float*)d_in[0];
  const float* Wq = (const float*)d_in[1];
  const float* bq = (const float*)d_in[2];
  const float* Wk = (const float*)d_in[3];
  const float* bk = (const float*)d_in[4];
  const float* Wv = (const float*)d_in[5];
  const float* bv = (const float*)d_in[6];
  float* out = (float*)d_out;

  char* p = (char*)d_ws;
  const size_t szQK = (size_t)2 * NPIX * CP * 2;
  unsigned short* QH = (unsigned short*)p; p += szQK;
  unsigned short* KH = (unsigned short*)p; p += szQK;
  unsigned short* VG = (unsigned short*)p; p += (size_t)2 * 80 * NPIX * 2;
  float* NUM = (float*)p; p += (size_t)SPLITS * 2 * 18 * NPIX * 4;   // 10.6 MB
  float* LPART = (float*)p; p += (size_t)SPLITS * 2 * NPIX * 4;      // 0.6 MB

  qkv_kernel<<<864, 256, 0, stream>>>(x, Wq, Wk, Wv, bq, bk, bv, QH, KH, VG);
  flash_kernel<<<FGRID, 256, 0, stream>>>(x, QH, KH, VG, NUM, LPART);
  combine_pool_kernel<<<(2 * 18 * (NPIX / 4) + 255) / 256, 256, 0, stream>>>(
      NUM, LPART, out);
}